// Round 10
// baseline (239.143 us; speedup 1.0000x reference)
//
#include <hip/hip_runtime.h>
#include <hip/hip_fp16.h>
#include <math.h>

#define N_NODES 50000
#define SLICE_SZ 6250          // N_NODES / 8 XCDs

__device__ __forceinline__ void fma4(float4& a, float w, const float4& v) {
    a.x += w * v.x; a.y += w * v.y; a.z += w * v.z; a.w += w * v.w;
}

struct h2x2 { __half2 a, b; };   // 8 bytes = 4 halves

// ---------------- degree histogram + per-edge rank ----------------
__global__ void count_kernel(const int* __restrict__ dst, int E,
                             int* __restrict__ counts, int* __restrict__ rank) {
    int i = blockIdx.x * blockDim.x + threadIdx.x;
    if (i < E) rank[i] = atomicAdd(&counts[dst[i]], 1);
}

// ---------------- block-level exclusive scan ----------------
__global__ void scan_block_kernel(const int* __restrict__ in, int n,
                                  int* __restrict__ outEx, int* __restrict__ blocksum) {
    __shared__ int s[256];
    int t = threadIdx.x, i = blockIdx.x * 256 + t;
    int v = (i < n) ? in[i] : 0;
    s[t] = v;
    __syncthreads();
    for (int off = 1; off < 256; off <<= 1) {
        int x = (t >= off) ? s[t - off] : 0;
        __syncthreads();
        s[t] += x;
        __syncthreads();
    }
    if (i < n) outEx[i] = s[t] - v;
    if (t == 255 && blocksum) blocksum[blockIdx.x] = s[255];
}

__global__ void finalize_kernel(const int* __restrict__ counts, const int* __restrict__ blocksum,
                                int n, int E, int* __restrict__ row_ptr,
                                float* __restrict__ dinv) {
    int i = blockIdx.x * blockDim.x + threadIdx.x;
    if (i < n) {
        row_ptr[i] += blocksum[i >> 8];
        dinv[i] = rsqrtf((float)(counts[i] + 1));   // +1 self-loop
        if (i == 0) row_ptr[n] = E;
    }
}

// ---------------- XCD-sliced, atomic-free CSR fill ----------------
__global__ void fill2_kernel(const int* __restrict__ src, const int* __restrict__ dst,
                             const int* __restrict__ rank, int E,
                             const int* __restrict__ row_ptr, const float* __restrict__ dinv,
                             int2* __restrict__ edges) {
    const int slice = blockIdx.x & 7;
    const int chunk = blockIdx.x >> 3;
    const int CS = (((E + 255) >> 8) + 3) & ~3;      // chunk size, multiple of 4
    const int lo = chunk * CS;
    const int hi = min(E, lo + CS);
    const int slo = slice * SLICE_SZ, shi = slo + SLICE_SZ;
    if (lo >= E) return;
    const int quad_end = lo + ((hi - lo) & ~3);
    for (int i = lo + threadIdx.x * 4; i + 3 < quad_end + 4 && i + 3 < hi + 4 && i < quad_end; i += 1024) {
        int4 d4 = *(const int4*)&dst[i];
        #pragma unroll
        for (int k = 0; k < 4; ++k) {
            int d = (&d4.x)[k];
            if (d >= slo && d < shi) {
                int s = src[i + k];
                int p = row_ptr[d] + rank[i + k];
                edges[p] = make_int2(s, __float_as_int(dinv[s] * dinv[d]));
            }
        }
    }
    for (int i = quad_end + threadIdx.x; i < hi; i += 256) {   // scalar tail
        int d = dst[i];
        if (d >= slo && d < shi) {
            int s = src[i];
            int p = row_ptr[d] + rank[i];
            edges[p] = make_int2(s, __float_as_int(dinv[s] * dinv[d]));
        }
    }
}

// ---------------- fp32 GEMM: C[n,DOUT] = A[n,DIN] @ W[DIN,DOUT] ----------------
// OMODE 0: fp32 flat. OMODE 1: fp16 PLANAR (plane h = cols [32h,32h+32) for all
// rows, contiguous 3.2MB -- so each gather pass's working set is its own plane;
// interleaved halves would share 128B L2 lines and defeat the split).
// OMODE 2: fp16 flat.
template<int DIN, int DOUT, int BM, int KC, int OMODE>
__global__ __launch_bounds__(256, 2) void gemm_kernel(const float* __restrict__ A,
                                                      const float* __restrict__ W,
                                                      void* __restrict__ Cv, int n) {
    constexpr int NCG = DOUT / 4;
    constexpr int NRG = BM / 4;
    static_assert(NCG * NRG == 256, "thread mapping");
    constexpr int KG = KC / 4;
    constexpr int RSTEP = 256 / KG;
    __shared__ __align__(16) float ws[DIN * DOUT];
    __shared__ __align__(16) float xs[KC][BM + 4];
    const int t = threadIdx.x;
    for (int i = 4 * t; i < DIN * DOUT; i += 1024)
        *(float4*)&ws[i] = *(const float4*)&W[i];
    const int rowbase = blockIdx.x * BM;
    const int r0 = (t / NCG) * 4;
    const int c0 = (t % NCG) * 4;
    const int lk = (t % KG) * 4;
    const int lr = t / KG;
    float acc[4][4] = {};
    for (int kc = 0; kc < DIN; kc += KC) {
        __syncthreads();
        #pragma unroll
        for (int r = lr; r < BM; r += RSTEP) {
            int row = rowbase + r;
            if (row >= n) row = n - 1;
            float4 v = *(const float4*)&A[(size_t)row * DIN + kc + lk];
            xs[lk + 0][r] = v.x; xs[lk + 1][r] = v.y;
            xs[lk + 2][r] = v.z; xs[lk + 3][r] = v.w;
        }
        __syncthreads();
        #pragma unroll 8
        for (int k = 0; k < KC; ++k) {
            float ar[4], wr[4];
            *(float4*)ar = *(const float4*)&xs[k][r0];
            *(float4*)wr = *(const float4*)&ws[(kc + k) * DOUT + c0];
            #pragma unroll
            for (int i = 0; i < 4; ++i)
                #pragma unroll
                for (int j = 0; j < 4; ++j)
                    acc[i][j] += ar[i] * wr[j];
        }
    }
    #pragma unroll
    for (int i = 0; i < 4; ++i) {
        int row = rowbase + r0 + i;
        if (row < n) {
            if constexpr (OMODE == 0) {
                float4 v = make_float4(acc[i][0], acc[i][1], acc[i][2], acc[i][3]);
                *(float4*)&((float*)Cv)[(size_t)row * DOUT + c0] = v;
            } else {
                union { uint2 u; __half2 h[2]; } pk;
                pk.h[0] = __floats2half2_rn(acc[i][0], acc[i][1]);
                pk.h[1] = __floats2half2_rn(acc[i][2], acc[i][3]);
                if constexpr (OMODE == 1) {
                    const int hp = c0 >> 5, c = c0 & 31;
                    *(uint2*)((__half*)Cv + (size_t)hp * ((size_t)n << 5)
                              + (size_t)row * 32 + c) = pk.u;
                } else {
                    *(uint2*)((__half*)Cv + (size_t)row * DOUT + c0) = pk.u;
                }
            }
        }
    }
}

// ---------------- layer-1 gather, one 32-feature half (L2-resident plane) ----------------
// Wave per node-quad; lanes = 8 fg (8B = 4 halves) x 8 ways. The plane is
// 3.2MB < 4MB per-XCD L2: random row gathers hit L2 (~220cy) instead of the
// ~950cy effective latency measured for the 6.4MB table (the round-9 limiter).
__global__ __launch_bounds__(256) void gather64_pass_kernel(
        const __half* __restrict__ plane,       // [n][32] halves, one feature half
        const int* __restrict__ row_ptr, const int2* __restrict__ edges,
        const float* __restrict__ dinv, const float* __restrict__ b1h,
        float* __restrict__ h1, int n, int half) {
    const int t = threadIdx.x;
    const int lane = t & 63;
    const int wid = t >> 6;
    const int fg = lane & 7, way = lane >> 3;
    const h2x2* __restrict__ P = (const h2x2*)plane;   // 8 units of 8B per row
    for (int it = 0; it < 4; ++it) {
        const int node = blockIdx.x * 16 + wid * 4 + it;
        if (node >= n) break;                       // wave-uniform
        const int start = row_ptr[node];
        const int deg = row_ptr[node + 1] - start;
        const int K = deg + 1;                      // + self record
        int2 rec;
        if (lane == 0) {
            float dv = dinv[node];
            rec = make_int2(node, __float_as_int(dv * dv));
        } else if (lane <= deg) {
            rec = edges[start + lane - 1];
        } else {
            rec = make_int2(node, 0);               // weight-0 pad
        }
        float4 acc = make_float4(0.f, 0.f, 0.f, 0.f);
        const int KP = (min(K, 64) + 7) & ~7;
        int k = way;
        #define GP_STEP(kk)                                                    \
            { int sv = __shfl(rec.x, (kk), 64);                                \
              float wgt = __int_as_float(__shfl(rec.y, (kk), 64));             \
              h2x2 rr = P[(size_t)sv * 8 + fg];                                \
              float2 f0 = __half22float2(rr.a), f1 = __half22float2(rr.b);     \
              acc.x += wgt * f0.x; acc.y += wgt * f0.y;                        \
              acc.z += wgt * f1.x; acc.w += wgt * f1.y; }
        for (; k + 8 < KP; k += 16) { GP_STEP(k) GP_STEP(k + 8) }
        for (; k < KP; k += 8) GP_STEP(k)
        #undef GP_STEP
        for (int kk = 64 + way; kk < K; kk += 8) {  // deg>63: direct (never in practice)
            int2 p = edges[start + kk - 1];
            float wgt = __int_as_float(p.y);
            h2x2 rr = P[(size_t)p.x * 8 + fg];
            float2 f0 = __half22float2(rr.a), f1 = __half22float2(rr.b);
            acc.x += wgt * f0.x; acc.y += wgt * f0.y;
            acc.z += wgt * f1.x; acc.w += wgt * f1.y;
        }
        #pragma unroll
        for (int m = 8; m <= 32; m <<= 1) {
            acc.x += __shfl_xor(acc.x, m, 64);
            acc.y += __shfl_xor(acc.y, m, 64);
            acc.z += __shfl_xor(acc.z, m, 64);
            acc.w += __shfl_xor(acc.w, m, 64);
        }
        if (way == 0) {
            float4 b = ((const float4*)b1h)[fg];
            float4 h;
            h.x = fmaxf(acc.x + b.x, 0.f);
            h.y = fmaxf(acc.y + b.y, 0.f);
            h.z = fmaxf(acc.z + b.z, 0.f);
            h.w = fmaxf(acc.w + b.w, 0.f);
            *(float4*)&h1[(size_t)node * 64 + half * 32 + 4 * fg] = h;
        }
    }
}

// ---------------- layer-2 gather (fp16 3.2MB L2-resident table) + attention ----------------
// Wave per node-quad; lanes = 8 fg (4 halves) x 8 ways.
__global__ __launch_bounds__(256) void gather32_final_kernel(
        const __half* __restrict__ XWh, const int* __restrict__ row_ptr,
        const int2* __restrict__ edges, const float* __restrict__ dinv,
        const float* __restrict__ b2, const float* __restrict__ aw,
        const float* __restrict__ ab, float* __restrict__ out, int n) {
    const int t = threadIdx.x;
    const int lane = t & 63;
    const int wid = t >> 6;
    const int fg = lane & 7, way = lane >> 3;
    const h2x2* __restrict__ P = (const h2x2*)XWh;
    for (int it = 0; it < 4; ++it) {
        const int node = blockIdx.x * 16 + wid * 4 + it;
        if (node >= n) break;
        const int start = row_ptr[node];
        const int deg = row_ptr[node + 1] - start;
        const int K = deg + 1;
        int2 rec;
        if (lane == 0) {
            float dv = dinv[node];
            rec = make_int2(node, __float_as_int(dv * dv));
        } else if (lane <= deg) {
            rec = edges[start + lane - 1];
        } else {
            rec = make_int2(node, 0);
        }
        float4 acc = make_float4(0.f, 0.f, 0.f, 0.f);
        const int KP = (min(K, 64) + 7) & ~7;
        int k = way;
        #define G32_STEP(kk)                                                   \
            { int sv = __shfl(rec.x, (kk), 64);                                \
              float wgt = __int_as_float(__shfl(rec.y, (kk), 64));             \
              h2x2 rr = P[(size_t)sv * 8 + fg];                                \
              float2 f0 = __half22float2(rr.a), f1 = __half22float2(rr.b);     \
              acc.x += wgt * f0.x; acc.y += wgt * f0.y;                        \
              acc.z += wgt * f1.x; acc.w += wgt * f1.y; }
        for (; k + 8 < KP; k += 16) { G32_STEP(k) G32_STEP(k + 8) }
        for (; k < KP; k += 8) G32_STEP(k)
        #undef G32_STEP
        for (int kk = 64 + way; kk < K; kk += 8) {  // deg>63: direct (never in practice)
            int2 p = edges[start + kk - 1];
            float wgt = __int_as_float(p.y);
            h2x2 rr = P[(size_t)p.x * 8 + fg];
            float2 f0 = __half22float2(rr.a), f1 = __half22float2(rr.b);
            acc.x += wgt * f0.x; acc.y += wgt * f0.y;
            acc.z += wgt * f1.x; acc.w += wgt * f1.y;
        }
        #pragma unroll
        for (int m = 8; m <= 32; m <<= 1) {
            acc.x += __shfl_xor(acc.x, m, 64);
            acc.y += __shfl_xor(acc.y, m, 64);
            acc.z += __shfl_xor(acc.z, m, 64);
            acc.w += __shfl_xor(acc.w, m, 64);
        }
        float4 b = ((const float4*)b2)[fg];
        float4 h;
        h.x = fmaxf(acc.x + b.x, 0.f);
        h.y = fmaxf(acc.y + b.y, 0.f);
        h.z = fmaxf(acc.z + b.z, 0.f);
        h.w = fmaxf(acc.w + b.w, 0.f);
        float4 a4 = ((const float4*)aw)[fg];
        float sca = h.x * a4.x + h.y * a4.y + h.z * a4.z + h.w * a4.w;
        sca += __shfl_xor(sca, 1, 64);
        sca += __shfl_xor(sca, 2, 64);
        sca += __shfl_xor(sca, 4, 64);
        float attn = 1.f / (1.f + __expf(-(sca + ab[0])));
        if (way == 0) {
            float4 r = make_float4(h.x * attn, h.y * attn, h.z * attn, h.w * attn);
            ((float4*)&out[(size_t)node * 32])[fg] = r;
        }
    }
}

extern "C" void kernel_launch(void* const* d_in, const int* in_sizes, int n_in,
                              void* d_out, int out_size, void* d_ws, size_t ws_size,
                              hipStream_t stream) {
    const float* x  = (const float*)d_in[0];
    const int*   ei = (const int*)d_in[1];
    const float* W1 = (const float*)d_in[2];
    const float* b1 = (const float*)d_in[3];
    const float* W2 = (const float*)d_in[4];
    const float* b2 = (const float*)d_in[5];
    const float* aw = (const float*)d_in[6];
    const float* ab = (const float*)d_in[7];
    float* out = (float*)d_out;

    const int n = N_NODES;
    const int E = in_sizes[1] / 2;
    const int* src = ei;
    const int* dst = ei + E;

    char* w = (char*)d_ws;
    auto alloc = [&](size_t bytes) { char* p = w; w += (bytes + 255) & ~(size_t)255; return p; };
    int*    counts   = (int*)   alloc((size_t)n * 4);
    int*    row_ptr  = (int*)   alloc((size_t)(n + 1) * 4);
    int*    rank     = (int*)   alloc((size_t)E * 4);
    int*    blocksum = (int*)   alloc(1024);
    float*  dinv     = (float*) alloc((size_t)n * 4);
    int2*   edges    = (int2*)  alloc((size_t)E * 8);
    __half* bufAh    = (__half*)alloc((size_t)n * 64 * 2);   // XW1 fp16, PLANAR 2x(n x 32)
    float*  h1buf    = (float*) alloc((size_t)n * 64 * 4);   // h1 fp32 (n x 64)
    __half* bufCh    = (__half*)alloc((size_t)n * 32 * 2);   // XW2 fp16 (n x 32), 3.2MB

    const int nb = (n + 255) / 256;

    hipMemsetAsync(counts, 0, (size_t)n * 4, stream);
    count_kernel<<<(E + 255) / 256, 256, 0, stream>>>(dst, E, counts, rank);
    scan_block_kernel<<<nb, 256, 0, stream>>>(counts, n, row_ptr, blocksum);
    scan_block_kernel<<<1, 256, 0, stream>>>(blocksum, nb, blocksum, nullptr);
    finalize_kernel<<<nb, 256, 0, stream>>>(counts, blocksum, n, E, row_ptr, dinv);
    fill2_kernel<<<256 * 8, 256, 0, stream>>>(src, dst, rank, E, row_ptr, dinv, edges);

    gemm_kernel<128, 64, 64, 32, 1><<<(n + 63) / 64, 256, 0, stream>>>(x, W1, bufAh, n);
    gather64_pass_kernel<<<(n + 15) / 16, 256, 0, stream>>>(
        bufAh,                 row_ptr, edges, dinv, b1,      h1buf, n, 0);
    gather64_pass_kernel<<<(n + 15) / 16, 256, 0, stream>>>(
        bufAh + (size_t)n * 32, row_ptr, edges, dinv, b1 + 32, h1buf, n, 1);
    gemm_kernel<64, 32, 128, 32, 2><<<(n + 127) / 128, 256, 0, stream>>>(h1buf, W2, bufCh, n);
    gather32_final_kernel<<<(n + 15) / 16, 256, 0, stream>>>(
        bufCh, row_ptr, edges, dinv, b2, aw, ab, out, n);
}